// Round 4
// baseline (419.935 us; speedup 1.0000x reference)
//
#include <hip/hip_runtime.h>

#define SLEN 2048
#define DIM  64
#define NH   8
#define TQ   16
#define NEG_INF -1e9f

typedef __attribute__((ext_vector_type(8))) short short8;
typedef __attribute__((ext_vector_type(4))) short short4v;
typedef __attribute__((ext_vector_type(4))) float f32x4;
typedef __attribute__((ext_vector_type(4))) int   i32x4;
typedef unsigned short ushort;

__device__ inline ushort f2bf(float x) {
    unsigned u = __float_as_uint(x);
    u += 0x7fffu + ((u >> 16) & 1u);          // RNE (inputs finite)
    return (ushort)(u >> 16);
}
__device__ inline float bf2f(ushort b) {
    return __uint_as_float(((unsigned)b) << 16);
}

// ---- fused precompute: K -> bf16 hi/lo; V -> V^T bf16 (blocks < 256) ----
__global__ __launch_bounds__(256)
void conv_kernel(const float* __restrict__ k, const float* __restrict__ v,
                 ushort* __restrict__ khi, ushort* __restrict__ klo,
                 ushort* __restrict__ vt)
{
    __shared__ ushort sT[64][70];
    const int bx = blockIdx.x;         // 1024
    const int t  = threadIdx.x;
    {   // K hi/lo split, 4 elem/thread, fully coalesced
        int i4 = bx * 256 + t;
        float4 x = ((const float4*)k)[i4];
        ushort h0 = f2bf(x.x), h1 = f2bf(x.y), h2 = f2bf(x.z), h3 = f2bf(x.w);
        ushort4 hi = {h0, h1, h2, h3};
        ushort4 lo = {f2bf(x.x - bf2f(h0)), f2bf(x.y - bf2f(h1)),
                      f2bf(x.z - bf2f(h2)), f2bf(x.w - bf2f(h3))};
        ((ushort4*)khi)[i4] = hi;
        ((ushort4*)klo)[i4] = lo;
    }
    if (bx < 256) {   // V transpose via LDS tile
        const int h  = bx >> 5;
        const int st = bx & 31;
        const int r0 = t >> 4;
        const int c  = (t & 15) * 4;
        #pragma unroll
        for (int rr = r0; rr < 64; rr += 16) {
            float4 x = *(const float4*)(v + ((size_t)(h * SLEN + st * 64 + rr)) * DIM + c);
            sT[c + 0][rr] = f2bf(x.x);
            sT[c + 1][rr] = f2bf(x.y);
            sT[c + 2][rr] = f2bf(x.z);
            sT[c + 3][rr] = f2bf(x.w);
        }
        __syncthreads();
        const int d  = t >> 2;
        const int s0 = (t & 3) * 16;
        short8 a = *(const short8*)(&sT[d][s0]);
        short8 b = *(const short8*)(&sT[d][s0 + 8]);
        ushort* dst = vt + ((size_t)(h * DIM + d)) * SLEN + st * 64 + s0;
        *(short8*)(dst)     = a;
        *(short8*)(dst + 8) = b;
    }
}

// ---- main: one block = (head, 16 q-rows); 8 waves; S^T-layout MFMA ----
__global__ __launch_bounds__(512, 2)
void attn_mfma_kernel(const float* __restrict__ q,
                      const ushort* __restrict__ khi,
                      const ushort* __restrict__ klo,
                      const ushort* __restrict__ vt,
                      const float* __restrict__ sph,
                      const int*   __restrict__ mask,
                      float* __restrict__ out,     // [H,S,D]
                      float* __restrict__ p_out)   // [H,S,S]
{
    __shared__ ushort sP[TQ][SLEN + 8];   // p tile bf16
    __shared__ ushort sQhi[TQ][72];
    __shared__ ushort sQlo[TQ][72];
    __shared__ float sMax[TQ][8];
    __shared__ float sSum[TQ][8];
    __shared__ float sC[4][TQ][16];

    const int tid  = threadIdx.x;
    const int wave = tid >> 6;
    const int lane = tid & 63;
    const int quad = lane >> 4;
    const int l16  = lane & 15;
    const int bx   = blockIdx.x;
    const int h    = bx & 7;          // head == XCD (round-robin dispatch)
    const int qr0  = (bx >> 3) * TQ;

    // ---- Q tile load + hi/lo split into LDS ----
    {
        int e = tid * 2;
        int r = e >> 6, d = e & 63;
        float2 qv = *(const float2*)(q + ((size_t)(h * SLEN + qr0 + r)) * DIM + d);
        ushort h0 = f2bf(qv.x), h1 = f2bf(qv.y);
        sQhi[r][d]     = h0;
        sQhi[r][d + 1] = h1;
        sQlo[r][d]     = f2bf(qv.x - bf2f(h0));
        sQlo[r][d + 1] = f2bf(qv.y - bf2f(h1));
    }
    __syncthreads();

    // Q fragments (now the B operand): B[k=quad*8+u][n=l16] = Q[l16][quad*8+u]
    short8 qh0 = *(const short8*)(&sQhi[l16][quad * 8]);
    short8 qh1 = *(const short8*)(&sQhi[l16][32 + quad * 8]);
    short8 ql0 = *(const short8*)(&sQlo[l16][quad * 8]);
    short8 ql1 = *(const short8*)(&sQlo[l16][32 + quad * 8]);

    const int n0 = wave * 256;        // this wave's 256 k-columns

    f32x4 c[16];
    #pragma unroll
    for (int t = 0; t < 16; ++t) c[t] = (f32x4){0.f, 0.f, 0.f, 0.f};

    // ---- QK^T, swapped operands: c[t] = S^T tile ----
    // D[row=quad*4+j = kcol][col=l16 = qrow]
    #pragma unroll
    for (int t = 0; t < 16; ++t) {
        const size_t krow = ((size_t)(h * SLEN + n0 + t * 16 + l16)) * DIM + quad * 8;
        short8 kh0 = *(const short8*)(khi + krow);
        short8 kh1 = *(const short8*)(khi + krow + 32);
        short8 kl0 = *(const short8*)(klo + krow);
        short8 kl1 = *(const short8*)(klo + krow + 32);
        c[t] = __builtin_amdgcn_mfma_f32_16x16x32_bf16(kh0, qh0, c[t], 0, 0, 0);
        c[t] = __builtin_amdgcn_mfma_f32_16x16x32_bf16(kh1, qh1, c[t], 0, 0, 0);
        c[t] = __builtin_amdgcn_mfma_f32_16x16x32_bf16(kh0, ql0, c[t], 0, 0, 0);
        c[t] = __builtin_amdgcn_mfma_f32_16x16x32_bf16(kh1, ql1, c[t], 0, 0, 0);
        c[t] = __builtin_amdgcn_mfma_f32_16x16x32_bf16(kl0, qh0, c[t], 0, 0, 0);
        c[t] = __builtin_amdgcn_mfma_f32_16x16x32_bf16(kl1, qh1, c[t], 0, 0, 0);
    }

    // Per-thread score coords: row = l16, cols = n0 + t*16 + quad*4 + j
    const size_t prow = ((size_t)(h * SLEN) + qr0 + l16) * SLEN + n0 + quad * 4;

    // ---- wide sph/mask prefetch: 32 x 16B NT loads, pinned above apply ----
    f32x4 sv[16];
    i32x4 mv[16];
    #pragma unroll
    for (int t = 0; t < 16; ++t) {
        sv[t] = __builtin_nontemporal_load((const f32x4*)(sph  + prow + t * 16));
        mv[t] = __builtin_nontemporal_load((const i32x4*)(mask + prow + t * 16));
    }
    __builtin_amdgcn_sched_barrier(0);

    float rmax = -3.4e38f;
    #pragma unroll
    for (int t = 0; t < 16; ++t) {
        #pragma unroll
        for (int j = 0; j < 4; ++j) {
            float s = c[t][j] * 0.125f * sv[t][j];
            s = (mv[t][j] == 0) ? NEG_INF : s;
            c[t][j] = s;
            rmax = fmaxf(rmax, s);
        }
    }
    rmax = fmaxf(rmax, __shfl_xor(rmax, 16));
    rmax = fmaxf(rmax, __shfl_xor(rmax, 32));
    if (lane < 16) sMax[l16][wave] = rmax;
    __syncthreads();

    float M = sMax[l16][0];
    #pragma unroll
    for (int w = 1; w < 8; ++w) M = fmaxf(M, sMax[l16][w]);

    float rsum = 0.f;
    #pragma unroll
    for (int t = 0; t < 16; ++t) {
        #pragma unroll
        for (int j = 0; j < 4; ++j) {
            float e = __expf(c[t][j] - M);
            c[t][j] = e;
            rsum += e;
        }
    }
    rsum += __shfl_xor(rsum, 16);
    rsum += __shfl_xor(rsum, 32);
    if (lane < 16) sSum[l16][wave] = rsum;
    __syncthreads();

    float ssum = 0.f;
    #pragma unroll
    for (int w = 0; w < 8; ++w) ssum += sSum[l16][w];
    const float inv = 1.0f / ssum;

    // ---- p -> sP (bf16, LDS); global p store deferred past PV ----
    #pragma unroll
    for (int t = 0; t < 16; ++t) {
        short4v pb;
        #pragma unroll
        for (int j = 0; j < 4; ++j) pb[j] = (short)f2bf(c[t][j] * inv);
        *(short4v*)(&sP[l16][n0 + t * 16 + quad * 4]) = pb;
    }
    __syncthreads();

    // ---- PV: wave -> (d-tile, k-half); 32 k-steps of 32 ----
    const int ntile = wave & 3;
    const int khalf = wave >> 2;
    f32x4 o = (f32x4){0.f, 0.f, 0.f, 0.f};
    const ushort* vb = vt + ((size_t)(h * DIM + ntile * 16 + l16)) * SLEN
                          + khalf * 1024 + quad * 8;
    #pragma unroll 8
    for (int s = 0; s < 32; ++s) {
        short8 a = *(const short8*)(&sP[l16][khalf * 1024 + s * 32 + quad * 8]);
        short8 b = *(const short8*)(vb + s * 32);
        o = __builtin_amdgcn_mfma_f32_16x16x32_bf16(a, b, o, 0, 0, 0);
    }
    if (wave >= 4) {
        #pragma unroll
        for (int j = 0; j < 4; ++j) sC[ntile][quad * 4 + j][l16] = o[j];
    }

    // ---- wide NT p_out stores (overlap with PV completion / sC barrier) ----
    #pragma unroll
    for (int t = 0; t < 16; ++t) {
        f32x4 p4;
        #pragma unroll
        for (int j = 0; j < 4; ++j) p4[j] = c[t][j] * inv;
        __builtin_nontemporal_store(p4, (f32x4*)(p_out + prow + t * 16));
    }
    __syncthreads();

    if (wave < 4) {
        #pragma unroll
        for (int j = 0; j < 4; ++j) {
            float r = o[j] + sC[ntile][quad * 4 + j][l16];
            out[((size_t)(h * SLEN) + qr0 + quad * 4 + j) * DIM + ntile * 16 + l16] = r;
        }
    }
}

extern "C" void kernel_launch(void* const* d_in, const int* in_sizes, int n_in,
                              void* d_out, int out_size, void* d_ws, size_t ws_size,
                              hipStream_t stream) {
    const float* q    = (const float*)d_in[0];
    const float* k    = (const float*)d_in[1];
    const float* v    = (const float*)d_in[2];
    const float* sph  = (const float*)d_in[3];
    const int*   mask = (const int*)d_in[4];
    float* out   = (float*)d_out;                       // [8,2048,64]
    float* p_out = out + (size_t)NH * SLEN * DIM;       // [8,2048,2048]

    const size_t nkv = (size_t)NH * SLEN * DIM;         // 1,048,576
    ushort* khi = (ushort*)d_ws;                        // 2 MB
    ushort* klo = khi + nkv;                            // 2 MB
    ushort* vt  = klo + nkv;                            // 2 MB

    hipLaunchKernelGGL(conv_kernel, dim3(nkv / 4 / 256), dim3(256), 0, stream,
                       k, v, khi, klo, vt);
    hipLaunchKernelGGL(attn_mfma_kernel, dim3(NH * (SLEN / TQ)), dim3(512), 0, stream,
                       q, khi, klo, vt, sph, mask, out, p_out);
}